// Round 1
// baseline (254.799 us; speedup 1.0000x reference)
//
#include <hip/hip_runtime.h>
#include <hip/hip_bf16.h>

// Residual_Comb_Conv: B=2048, C_IN=64, C_MID=64, C_OUT=128, R=60, K=13
// Strategy: per-batch fused bf16 MFMA GEMMs.
//   z = relu(bn(x)) precomputed per batch (gather commutes with elementwise).
//   z stored column-major in LDS (64 ch contiguous per r', 144 B stride) so the
//   gathered B-fragment is one ds_read_b128 per lane.
//   Weights pre-transposed to bf16 [o][ks][c] so A-fragments are 16B global loads
//   (L2-resident), prefetched one K-step ahead. Conv2+Conv3 fused along K.

typedef __attribute__((ext_vector_type(8))) short bf16x8;
typedef __attribute__((ext_vector_type(4))) float f32x4;
typedef __attribute__((ext_vector_type(4))) unsigned short us4;

#define EPSV 1e-5f
#define ZSTRIDE 72            // elements per z column: 64 ch + 8 pad (144 B)
#define ZCOLBYTES 144
#define ZELEMS (64 * ZSTRIDE) // 4608 elements per z buffer

__device__ __forceinline__ unsigned short f2bf(float f) {
  unsigned int u = __builtin_bit_cast(unsigned int, f);
  u += 0x7FFFu + ((u >> 16) & 1u);   // round-to-nearest-even
  return (unsigned short)(u >> 16);
}

// ---- prep: W1 [64][64][13] -> W1t bf16 [64][13*64] (kk = ks*64 + c)
//           W2|W3 [128][64][13] -> W23t bf16 [128][26*64] (f-source then x-source)
__global__ void prep_w(const float* __restrict__ W1, const float* __restrict__ W2,
                       const float* __restrict__ W3, unsigned short* __restrict__ W1t,
                       unsigned short* __restrict__ W23t) {
  int gid = blockIdx.x * 256 + threadIdx.x;
  if (gid < 64 * 832) {
    int o = gid / 832;
    int kk = gid - o * 832;
    int ks = kk >> 6, c = kk & 63;
    W1t[gid] = f2bf(W1[(o * 64 + c) * 13 + ks]);
  } else {
    int idx = gid - 64 * 832;
    int o = idx / 1664;
    int kk = idx - o * 1664;
    int kq = kk >> 6, c = kk & 63;
    float v = (kq < 13) ? W2[(o * 64 + c) * 13 + kq] : W3[(o * 64 + c) * 13 + (kq - 13)];
    W23t[idx] = f2bf(v);
  }
}

#define MFMA __builtin_amdgcn_mfma_f32_16x16x32_bf16

__global__ __launch_bounds__(256, 2) void fused_k(
    const float* __restrict__ x, const int* __restrict__ nei,
    const float* __restrict__ g1, const float* __restrict__ be1,
    const float* __restrict__ mu1, const float* __restrict__ va1,
    const float* __restrict__ c1,
    const float* __restrict__ g2, const float* __restrict__ be2,
    const float* __restrict__ mu2, const float* __restrict__ va2,
    const float* __restrict__ c2,
    const float* __restrict__ g3, const float* __restrict__ be3,
    const float* __restrict__ mu3, const float* __restrict__ va3,
    const float* __restrict__ c3,
    const unsigned short* __restrict__ W1t,
    const unsigned short* __restrict__ W23t,
    float* __restrict__ out)
{
  __shared__ unsigned short z1[ZELEMS];      // act1(x), column-major [r'][c]
  __shared__ unsigned short zz[2 * ZELEMS];  // z2 = act2(f) then z3 = act3(x)
  __shared__ int lneio[780];                 // nei[r*13+k] * 144 (byte offset)
  __shared__ float pp[6 * 64];               // a1,b1',a2,b2',a3,b3'
  __shared__ float pcc[128];                 // c2 + c3

  const int tid  = threadIdx.x;
  const int wave = tid >> 6;
  const int lane = tid & 63;
  const int quad = lane >> 4;
  const int nl   = lane & 15;

  // ---- fold BN params (recomputed per block; trivial vs. GEMM work)
  if (tid < 64) {
    float a1v = g1[tid] * rsqrtf(va1[tid] + EPSV);
    pp[tid]       = a1v;
    pp[64 + tid]  = be1[tid] - mu1[tid] * a1v;
    float a2v = g2[tid] * rsqrtf(va2[tid] + EPSV);
    pp[128 + tid] = a2v;
    pp[192 + tid] = be2[tid] - mu2[tid] * a2v + a2v * c1[tid]; // fold conv1 bias
    float a3v = g3[tid] * rsqrtf(va3[tid] + EPSV);
    pp[256 + tid] = a3v;
    pp[320 + tid] = be3[tid] - mu3[tid] * a3v;
  } else if (tid >= 128) {
    pcc[tid - 128] = c2[tid - 128] + c3[tid - 128];
  }
  for (int i = tid; i < 780; i += 256) lneio[i] = nei[i] * ZCOLBYTES;
  __syncthreads();

  // ---- build z1 = act1(x), z3 = act3(x) (relu/affine commute with gather)
  const float* xb = x + blockIdx.x * (64 * 60);
  unsigned short* z3p = zz + ZELEMS;
  for (int i = tid; i < 64 * 60; i += 256) {
    int c = i / 60;
    int r = i - c * 60;
    float xv = xb[i];
    z1[r * ZSTRIDE + c]  = f2bf(fmaxf(fmaf(xv, pp[c],       pp[64 + c]),  0.f));
    z3p[r * ZSTRIDE + c] = f2bf(fmaxf(fmaf(xv, pp[256 + c], pp[320 + c]), 0.f));
  }
  __syncthreads();

  int rcl13[4];
  #pragma unroll
  for (int nt = 0; nt < 4; nt++) {
    int r = nt * 16 + nl;
    rcl13[nt] = (r < 60 ? r : 59) * 13;   // clamp pad columns; masked at store
  }

  // ---- stage 1: F[64x64] = W1t[64x832] . H1(z1)   wave -> mtile=wave, 4 ntiles
  f32x4 acc1[4] = {};
  {
    const unsigned short* w1p = W1t + (wave * 16 + nl) * 832 + quad * 8;
    bf16x8 aC0 = *(const bf16x8*)(w1p);
    bf16x8 aC1 = *(const bf16x8*)(w1p + 32);
    const char* zb = (const char*)z1 + quad * 16;
    #pragma unroll 1
    for (int ks = 0; ks < 13; ks++) {
      int pf = (ks < 12 ? ks + 1 : 12) * 64;           // prefetch next ks
      bf16x8 aN0 = *(const bf16x8*)(w1p + pf);
      bf16x8 aN1 = *(const bf16x8*)(w1p + pf + 32);
      int no0 = lneio[rcl13[0] + ks];
      int no1 = lneio[rcl13[1] + ks];
      int no2 = lneio[rcl13[2] + ks];
      int no3 = lneio[rcl13[3] + ks];
      bf16x8 bb;
      bb = *(const bf16x8*)(zb + no0);      acc1[0] = MFMA(aC0, bb, acc1[0], 0, 0, 0);
      bb = *(const bf16x8*)(zb + no1);      acc1[1] = MFMA(aC0, bb, acc1[1], 0, 0, 0);
      bb = *(const bf16x8*)(zb + no2);      acc1[2] = MFMA(aC0, bb, acc1[2], 0, 0, 0);
      bb = *(const bf16x8*)(zb + no3);      acc1[3] = MFMA(aC0, bb, acc1[3], 0, 0, 0);
      bb = *(const bf16x8*)(zb + no0 + 64); acc1[0] = MFMA(aC1, bb, acc1[0], 0, 0, 0);
      bb = *(const bf16x8*)(zb + no1 + 64); acc1[1] = MFMA(aC1, bb, acc1[1], 0, 0, 0);
      bb = *(const bf16x8*)(zb + no2 + 64); acc1[2] = MFMA(aC1, bb, acc1[2], 0, 0, 0);
      bb = *(const bf16x8*)(zb + no3 + 64); acc1[3] = MFMA(aC1, bb, acc1[3], 0, 0, 0);
      aC0 = aN0; aC1 = aN1;
    }
  }

  // ---- act2(F) -> z2 (D layout: row o = quad*4+reg, col r = nl)
  {
    int ob = wave * 16 + quad * 4;
    float a20 = pp[128 + ob], a21 = pp[128 + ob + 1], a22 = pp[128 + ob + 2], a23 = pp[128 + ob + 3];
    float b20 = pp[192 + ob], b21 = pp[192 + ob + 1], b22 = pp[192 + ob + 2], b23 = pp[192 + ob + 3];
    #pragma unroll
    for (int nt = 0; nt < 4; nt++) {
      int r = nt * 16 + nl;
      us4 w;
      w.x = f2bf(fmaxf(fmaf(acc1[nt][0], a20, b20), 0.f));
      w.y = f2bf(fmaxf(fmaf(acc1[nt][1], a21, b21), 0.f));
      w.z = f2bf(fmaxf(fmaf(acc1[nt][2], a22, b22), 0.f));
      w.w = f2bf(fmaxf(fmaf(acc1[nt][3], a23, b23), 0.f));
      *(us4*)&zz[r * ZSTRIDE + ob] = w;    // 8B aligned
    }
  }
  __syncthreads();

  // ---- stage 2: OUT[128x64] = W23t[128x1664] . [H2(z2); H3(z3)]
  //      wave -> mtiles {wave*2, wave*2+1}, 4 ntiles
  f32x4 acc2[8] = {};
  {
    const unsigned short* wp0 = W23t + (wave * 32 + nl) * 1664 + quad * 8;
    const unsigned short* wp1 = wp0 + 16 * 1664;
    bf16x8 a0C0 = *(const bf16x8*)(wp0);
    bf16x8 a0C1 = *(const bf16x8*)(wp0 + 32);
    bf16x8 a1C0 = *(const bf16x8*)(wp1);
    bf16x8 a1C1 = *(const bf16x8*)(wp1 + 32);
    #pragma unroll 1
    for (int kt = 0; kt < 26; kt++) {          // kt = src*13 + ks
      int pf = (kt < 25 ? kt + 1 : 25) * 64;
      bf16x8 n00 = *(const bf16x8*)(wp0 + pf);
      bf16x8 n01 = *(const bf16x8*)(wp0 + pf + 32);
      bf16x8 n10 = *(const bf16x8*)(wp1 + pf);
      bf16x8 n11 = *(const bf16x8*)(wp1 + pf + 32);
      int ks = (kt < 13) ? kt : (kt - 13);
      const char* zb = (const char*)zz + ((kt < 13) ? 0 : 2 * ZELEMS) + quad * 16;
      int no0 = lneio[rcl13[0] + ks];
      int no1 = lneio[rcl13[1] + ks];
      int no2 = lneio[rcl13[2] + ks];
      int no3 = lneio[rcl13[3] + ks];
      bf16x8 bb;
      bb = *(const bf16x8*)(zb + no0);
      acc2[0] = MFMA(a0C0, bb, acc2[0], 0, 0, 0);
      acc2[4] = MFMA(a1C0, bb, acc2[4], 0, 0, 0);
      bb = *(const bf16x8*)(zb + no1);
      acc2[1] = MFMA(a0C0, bb, acc2[1], 0, 0, 0);
      acc2[5] = MFMA(a1C0, bb, acc2[5], 0, 0, 0);
      bb = *(const bf16x8*)(zb + no2);
      acc2[2] = MFMA(a0C0, bb, acc2[2], 0, 0, 0);
      acc2[6] = MFMA(a1C0, bb, acc2[6], 0, 0, 0);
      bb = *(const bf16x8*)(zb + no3);
      acc2[3] = MFMA(a0C0, bb, acc2[3], 0, 0, 0);
      acc2[7] = MFMA(a1C0, bb, acc2[7], 0, 0, 0);
      bb = *(const bf16x8*)(zb + no0 + 64);
      acc2[0] = MFMA(a0C1, bb, acc2[0], 0, 0, 0);
      acc2[4] = MFMA(a1C1, bb, acc2[4], 0, 0, 0);
      bb = *(const bf16x8*)(zb + no1 + 64);
      acc2[1] = MFMA(a0C1, bb, acc2[1], 0, 0, 0);
      acc2[5] = MFMA(a1C1, bb, acc2[5], 0, 0, 0);
      bb = *(const bf16x8*)(zb + no2 + 64);
      acc2[2] = MFMA(a0C1, bb, acc2[2], 0, 0, 0);
      acc2[6] = MFMA(a1C1, bb, acc2[6], 0, 0, 0);
      bb = *(const bf16x8*)(zb + no3 + 64);
      acc2[3] = MFMA(a0C1, bb, acc2[3], 0, 0, 0);
      acc2[7] = MFMA(a1C1, bb, acc2[7], 0, 0, 0);
      a0C0 = n00; a0C1 = n01; a1C0 = n10; a1C1 = n11;
    }
  }

  // ---- epilogue: out[b][o][r] = acc2 + (c2[o] + c3[o])
  float* outb = out + blockIdx.x * (128 * 60);
  #pragma unroll
  for (int mt = 0; mt < 2; mt++) {
    int ob = wave * 32 + mt * 16 + quad * 4;
    float q0 = pcc[ob], q1 = pcc[ob + 1], q2 = pcc[ob + 2], q3 = pcc[ob + 3];
    #pragma unroll
    for (int nt = 0; nt < 4; nt++) {
      int r = nt * 16 + nl;
      if (r < 60) {
        f32x4 a = acc2[mt * 4 + nt];
        outb[(ob + 0) * 60 + r] = a[0] + q0;
        outb[(ob + 1) * 60 + r] = a[1] + q1;
        outb[(ob + 2) * 60 + r] = a[2] + q2;
        outb[(ob + 3) * 60 + r] = a[3] + q3;
      }
    }
  }
}

extern "C" void kernel_launch(void* const* d_in, const int* in_sizes, int n_in,
                              void* d_out, int out_size, void* d_ws, size_t ws_size,
                              hipStream_t stream) {
  const float* x   = (const float*)d_in[0];
  const int*   nei = (const int*)d_in[1];
  const float* g1  = (const float*)d_in[2];
  const float* be1 = (const float*)d_in[3];
  const float* mu1 = (const float*)d_in[4];
  const float* va1 = (const float*)d_in[5];
  const float* W1  = (const float*)d_in[6];
  const float* c1  = (const float*)d_in[7];
  const float* g2  = (const float*)d_in[8];
  const float* be2 = (const float*)d_in[9];
  const float* mu2 = (const float*)d_in[10];
  const float* va2 = (const float*)d_in[11];
  const float* W2  = (const float*)d_in[12];
  const float* c2  = (const float*)d_in[13];
  const float* g3  = (const float*)d_in[14];
  const float* be3 = (const float*)d_in[15];
  const float* mu3 = (const float*)d_in[16];
  const float* va3 = (const float*)d_in[17];
  const float* W3  = (const float*)d_in[18];
  const float* c3  = (const float*)d_in[19];

  // workspace: W1t bf16 [64*832] then W23t bf16 [128*1664]  (~532 KB)
  unsigned short* W1t  = (unsigned short*)d_ws;
  unsigned short* W23t = W1t + 64 * 832;

  prep_w<<<1040, 256, 0, stream>>>(W1, W2, W3, W1t, W23t);
  fused_k<<<2048, 256, 0, stream>>>(x, nei, g1, be1, mu1, va1, c1,
                                    g2, be2, mu2, va2, c2,
                                    g3, be3, mu3, va3, c3,
                                    W1t, W23t, (float*)d_out);
}